// Round 1
// baseline (6204.107 us; speedup 1.0000x reference)
//
#include <hip/hip_runtime.h>

// GPT-2 small forward on gfx950. bf16 MFMA GEMMs, fp32 residual stream.
// Layout notes (HW-verified per guide):
//   mfma_f32_16x16x32_bf16: A/B frag: elem j of lane L = M[L&15][(L>>4)*8+j]
//   C/D: reg r of lane L = C[(L>>4)*4 + r][L&15]
// R1 change: weights pre-converted to bf16 once (cvt_k) -> gemm_k<BF16B=true>
// stages B with pure bit-repack instead of per-K-step f2bf (theory: VALU-bound
// staging). Fallback to f32-B path if workspace too small.

typedef __attribute__((ext_vector_type(4))) float f32x4;
typedef __attribute__((ext_vector_type(8))) short short8;
typedef __attribute__((ext_vector_type(4))) unsigned int u32x4;
typedef __attribute__((ext_vector_type(2))) unsigned int u32x2;

__device__ __forceinline__ float bf2f_u(unsigned int lo16){
  union { unsigned int i; float f; } v; v.i = lo16 << 16; return v.f;
}
__device__ __forceinline__ unsigned short f2bf(float x){
  union { float f; unsigned int i; } v; v.f = x;
  unsigned int i = v.i;
  return (unsigned short)((i + 0x7fffu + ((i >> 16) & 1u)) >> 16);
}
__device__ __forceinline__ int swz(int row){ return (row >> 1) & 3; }

// ---------------- f32 -> bf16 bulk convert ----------------
__global__ __launch_bounds__(256) void cvt_k(const float* __restrict__ src,
    unsigned short* __restrict__ dst, size_t n8){
  size_t i = (size_t)blockIdx.x * 256 + threadIdx.x;
  size_t stride = (size_t)gridDim.x * 256;
  for (; i < n8; i += stride){
    const f32x4* s = (const f32x4*)(src + i*8);
    f32x4 a = s[0], b = s[1];
    u32x4 o;
    o[0] = (unsigned int)f2bf(a[0]) | ((unsigned int)f2bf(a[1]) << 16);
    o[1] = (unsigned int)f2bf(a[2]) | ((unsigned int)f2bf(a[3]) << 16);
    o[2] = (unsigned int)f2bf(b[0]) | ((unsigned int)f2bf(b[1]) << 16);
    o[3] = (unsigned int)f2bf(b[2]) | ((unsigned int)f2bf(b[3]) << 16);
    *(u32x4*)(dst + i*8) = o;
  }
}

// ---------------- embedding ----------------
__global__ __launch_bounds__(256) void embed_k(const int* __restrict__ ids,
    const float* __restrict__ wte, const float* __restrict__ wpe, float* __restrict__ x){
  int tok = blockIdx.x, t = threadIdx.x;
  int id = ids[tok]; int pos = tok & 1023;
  const float* we = wte + (size_t)id * 768;
  const float* pe = wpe + (size_t)pos * 768;
  float* xo = x + (size_t)tok * 768;
  #pragma unroll
  for (int j = 0; j < 3; j++){ int c = t + j*256; xo[c] = we[c] + pe[c]; }
}

// ---------------- layernorm -> bf16 ----------------
__global__ __launch_bounds__(256) void ln_k(const float* __restrict__ X,
    const float* __restrict__ g, const float* __restrict__ bta, unsigned short* __restrict__ H){
  int row = blockIdx.x, t = threadIdx.x;
  const float* xr = X + (size_t)row * 768;
  float v0 = xr[t], v1 = xr[t+256], v2 = xr[t+512];
  float s = v0+v1+v2;
  float ss = v0*v0+v1*v1+v2*v2;
  #pragma unroll
  for (int o = 32; o > 0; o >>= 1){ s += __shfl_xor(s, o, 64); ss += __shfl_xor(ss, o, 64); }
  __shared__ float rs_[4], rq_[4];
  int w = t >> 6;
  if ((t & 63) == 0){ rs_[w] = s; rq_[w] = ss; }
  __syncthreads();
  s  = rs_[0]+rs_[1]+rs_[2]+rs_[3];
  ss = rq_[0]+rq_[1]+rq_[2]+rq_[3];
  float mu = s * (1.f/768.f);
  float var = ss * (1.f/768.f) - mu*mu;
  float r = rsqrtf(var + 1e-5f);
  unsigned short* ho = H + (size_t)row*768;
  float vv[3] = {v0, v1, v2};
  #pragma unroll
  for (int j=0;j<3;j++){ int c = t + j*256; ho[c] = f2bf((vv[j] - mu)*r*g[c] + bta[c]); }
}

// ---------------- GEMM: C[M,N] = A(bf16)[M,K] @ B (+bias)(+gelu)(+resid) ----------------
// BL=0: B is [K,N] row-major.  BL=1: B is [N,K] row-major (lm_head, B=wte).
// BF16B=1: B is pre-converted bf16; staging is bit-repack only (no f2bf).
template<int TM, int BL, bool RESID, bool GELU_ACT, bool OUTBF16, bool NGUARD, bool BF16B>
__global__ __launch_bounds__(256, 2) void gemm_k(
    const unsigned short* __restrict__ A, const void* __restrict__ Bw,
    const float* __restrict__ bias, const float* __restrict__ resid,
    void* __restrict__ Cp, int M, int N, int K)
{
  constexpr int BM = TM * 32;
  __shared__ __align__(16) unsigned short As[128*32];
  __shared__ __align__(16) unsigned short Bs[128*32];
  const int tid = threadIdx.x;
  const int m0 = blockIdx.x * BM, n0 = blockIdx.y * 128;
  const int lane = tid & 63, w = tid >> 6;
  const int quad = lane >> 4, lr = lane & 15;
  const int wm = (w >> 1) * (TM*16), wn = (w & 1) * 64;

  f32x4 acc[TM][4];
  #pragma unroll
  for (int i=0;i<TM;i++)
    #pragma unroll
    for (int j=0;j<4;j++) acc[i][j] = (f32x4)0.f;

  // staging registers
  u32x4 aReg[TM/2 > 0 ? TM/2 : 1];
  float bReg[16];
  u32x2 bRegH[4];
  u32x4 bRegQ[2];
  const int kb = (tid >> 5) * 4;        // BL==0
  const int nn = (tid & 31) * 4;        // BL==0
  const int nr = tid >> 1;              // BL==1
  const int kk = (tid & 1) * 16;        // BL==1

  auto loadA = [&](int k0){
    #pragma unroll
    for (int j = 0; j < TM/2; j++){
      int idx = tid * (TM/2) + j;
      int row = idx >> 2, b = idx & 3;
      aReg[j] = *(const u32x4*)(A + (size_t)(m0+row)*K + k0 + b*8);
    }
  };
  auto loadB = [&](int k0){
    if (BF16B){
      const unsigned short* Bh = (const unsigned short*)Bw;
      if (BL == 0){
        #pragma unroll
        for (int i=0;i<4;i++)
          bRegH[i] = *(const u32x2*)(Bh + (size_t)(k0+kb+i)*N + n0 + nn);
      } else {
        int gn = n0 + nr;
        if (!NGUARD || gn < N){
          bRegQ[0] = *(const u32x4*)(Bh + (size_t)gn*K + k0 + kk);
          bRegQ[1] = *(const u32x4*)(Bh + (size_t)gn*K + k0 + kk + 8);
        } else {
          bRegQ[0] = (u32x4)0u; bRegQ[1] = (u32x4)0u;
        }
      }
    } else {
      const float* Bf = (const float*)Bw;
      if (BL == 0){
        #pragma unroll
        for (int i=0;i<4;i++){
          f32x4 v = *(const f32x4*)(Bf + (size_t)(k0+kb+i)*N + n0 + nn);
          #pragma unroll
          for (int j=0;j<4;j++) bReg[i*4+j] = v[j];
        }
      } else {
        int gn = n0 + nr;
        if (!NGUARD || gn < N){
          #pragma unroll
          for (int q2=0;q2<4;q2++){
            f32x4 v = *(const f32x4*)(Bf + (size_t)gn*K + k0 + kk + q2*4);
            #pragma unroll
            for (int j=0;j<4;j++) bReg[q2*4+j] = v[j];
          }
        } else {
          #pragma unroll
          for (int q2=0;q2<16;q2++) bReg[q2] = 0.f;
        }
      }
    }
  };
  auto storeA = [&](){
    #pragma unroll
    for (int j=0;j<TM/2;j++){
      int idx = tid*(TM/2)+j;
      int row = idx>>2, b = idx&3;
      int off = row*64 + ((b ^ swz(row))<<4);
      *(u32x4*)((char*)As + off) = aReg[j];
    }
  };
  auto storeB = [&](){
    if (BF16B){
      if (BL == 0){
        int blk = kb >> 3;
        #pragma unroll
        for (int j=0;j<4;j++){
          int row = nn + j;
          unsigned int e0 = (bRegH[0][j>>1] >> ((j&1)*16)) & 0xffffu;
          unsigned int e1 = (bRegH[1][j>>1] >> ((j&1)*16)) & 0xffffu;
          unsigned int e2 = (bRegH[2][j>>1] >> ((j&1)*16)) & 0xffffu;
          unsigned int e3 = (bRegH[3][j>>1] >> ((j&1)*16)) & 0xffffu;
          int off = row*64 + ((blk ^ swz(row)) << 4) + (kb & 7)*2;
          u32x2 pv = {e0 | (e1 << 16), e2 | (e3 << 16)};
          *(u32x2*)((char*)Bs + off) = pv;
        }
      } else {
        #pragma unroll
        for (int half=0; half<2; half++){
          int blk = (kk >> 3) + half;
          int off = nr*64 + ((blk ^ swz(nr)) << 4);
          *(u32x4*)((char*)Bs + off) = bRegQ[half];
        }
      }
    } else {
      if (BL == 0){
        int blk = kb >> 3;
        #pragma unroll
        for (int j=0;j<4;j++){
          int row = nn + j;
          unsigned int lo = (unsigned int)f2bf(bReg[0*4+j]) | ((unsigned int)f2bf(bReg[1*4+j]) << 16);
          unsigned int hi = (unsigned int)f2bf(bReg[2*4+j]) | ((unsigned int)f2bf(bReg[3*4+j]) << 16);
          int off = row*64 + ((blk ^ swz(row)) << 4) + (kb & 7)*2;
          u32x2 pv = {lo, hi};
          *(u32x2*)((char*)Bs + off) = pv;
        }
      } else {
        int row = nr;
        #pragma unroll
        for (int half=0; half<2; half++){
          unsigned int w0 = (unsigned int)f2bf(bReg[half*8+0]) | ((unsigned int)f2bf(bReg[half*8+1])<<16);
          unsigned int w1 = (unsigned int)f2bf(bReg[half*8+2]) | ((unsigned int)f2bf(bReg[half*8+3])<<16);
          unsigned int w2 = (unsigned int)f2bf(bReg[half*8+4]) | ((unsigned int)f2bf(bReg[half*8+5])<<16);
          unsigned int w3 = (unsigned int)f2bf(bReg[half*8+6]) | ((unsigned int)f2bf(bReg[half*8+7])<<16);
          int blk = (kk >> 3) + half;
          int off = row*64 + ((blk ^ swz(row)) << 4);
          u32x4 pv = {w0,w1,w2,w3};
          *(u32x4*)((char*)Bs + off) = pv;
        }
      }
    }
  };

  loadA(0); loadB(0);
  const int nK = K / 32;
  for (int kt = 0; kt < nK; kt++){
    __syncthreads();
    storeA(); storeB();
    __syncthreads();
    if (kt + 1 < nK){ loadA((kt+1)*32); loadB((kt+1)*32); }
    short8 af[TM], bfr[4];
    #pragma unroll
    for (int i=0;i<TM;i++){
      int row = wm + i*16 + lr;
      af[i] = *(const short8*)((const char*)As + row*64 + ((quad ^ swz(row))<<4));
    }
    #pragma unroll
    for (int j=0;j<4;j++){
      int col = wn + j*16 + lr;
      bfr[j] = *(const short8*)((const char*)Bs + col*64 + ((quad ^ swz(col))<<4));
    }
    #pragma unroll
    for (int i=0;i<TM;i++)
      #pragma unroll
      for (int j=0;j<4;j++)
        acc[i][j] = __builtin_amdgcn_mfma_f32_16x16x32_bf16(af[i], bfr[j], acc[i][j], 0, 0, 0);
  }

  // epilogue
  #pragma unroll
  for (int i=0;i<TM;i++){
    #pragma unroll
    for (int j=0;j<4;j++){
      int col = n0 + wn + j*16 + lr;
      bool ok = !NGUARD || (col < N);
      float bv = 0.f;
      if (bias != nullptr && ok) bv = bias[col];
      #pragma unroll
      for (int r2=0;r2<4;r2++){
        int row = m0 + wm + i*16 + quad*4 + r2;
        float v = acc[i][j][r2] + bv;
        if (GELU_ACT){
          float x3 = v*v*v;
          v = 0.5f*v*(1.f + tanhf(0.7978845608028654f*(v + 0.044715f*x3)));
        }
        if (RESID && ok) v += resid[(size_t)row*N + col];
        if (ok){
          if (OUTBF16) ((unsigned short*)Cp)[(size_t)row*N + col] = f2bf(v);
          else         ((float*)Cp)[(size_t)row*N + col] = v;
        }
      }
    }
  }
}

// ---------------- causal attention (flash-style, fp32 vector) ----------------
__global__ __launch_bounds__(256, 2) void attn_k(const unsigned short* __restrict__ qkv,
                                                 unsigned short* __restrict__ O){
  __shared__ __align__(16) float qsT[64*64];          // [d][row], q pre-scaled
  __shared__ __align__(16) float ksT[64*64];          // [d][key]
  __shared__ __align__(16) float psT[64*64];          // [key][row]
  __shared__ __align__(16) unsigned short vsm[64*72]; // [key][d] bf16
  const int bh = blockIdx.x, qt = blockIdx.y;
  const int b = bh / 12, h = bh % 12;
  const int tid = threadIdx.x;
  const int rq = tid & 15, dg = tid >> 4;
  const int r0 = rq * 4, d0 = dg * 4;
  const int tr = tid >> 2, c16 = (tid & 3) * 16;

  { // stage Q (scaled by 1/sqrt(64))
    const unsigned short* src = qkv + (size_t)(b*1024 + qt*64 + tr)*2304 + h*64 + c16;
    u32x4 u0 = *(const u32x4*)src;
    u32x4 u1 = *(const u32x4*)(src + 8);
    #pragma unroll
    for (int i=0;i<4;i++){
      qsT[(c16 + i*2 + 0)*64 + tr] = bf2f_u(u0[i] & 0xffffu) * 0.125f;
      qsT[(c16 + i*2 + 1)*64 + tr] = bf2f_u(u0[i] >> 16)     * 0.125f;
      qsT[(c16 + 8 + i*2 + 0)*64 + tr] = bf2f_u(u1[i] & 0xffffu) * 0.125f;
      qsT[(c16 + 8 + i*2 + 1)*64 + tr] = bf2f_u(u1[i] >> 16)     * 0.125f;
    }
  }

  f32x4 oacc[4];
  #pragma unroll
  for (int i=0;i<4;i++) oacc[i] = (f32x4)0.f;
  f32x4 m4 = (f32x4)(-1e30f);
  f32x4 l4 = (f32x4)0.f;

  for (int kt = 0; kt <= qt; kt++){
    __syncthreads();
    { // stage K (transposed, f32) and V (bf16 raw copy)
      const unsigned short* ks_ = qkv + (size_t)(b*1024 + kt*64 + tr)*2304 + 768 + h*64 + c16;
      u32x4 k0 = *(const u32x4*)ks_;
      u32x4 k1 = *(const u32x4*)(ks_ + 8);
      #pragma unroll
      for (int i=0;i<4;i++){
        ksT[(c16 + i*2 + 0)*64 + tr] = bf2f_u(k0[i] & 0xffffu);
        ksT[(c16 + i*2 + 1)*64 + tr] = bf2f_u(k0[i] >> 16);
        ksT[(c16 + 8 + i*2 + 0)*64 + tr] = bf2f_u(k1[i] & 0xffffu);
        ksT[(c16 + 8 + i*2 + 1)*64 + tr] = bf2f_u(k1[i] >> 16);
      }
      const unsigned short* vs_ = ks_ + 768;
      u32x4 v0 = *(const u32x4*)vs_;
      u32x4 v1 = *(const u32x4*)(vs_ + 8);
      *(u32x4*)&vsm[tr*72 + c16] = v0;
      *(u32x4*)&vsm[tr*72 + c16 + 8] = v1;
    }
    __syncthreads();

    // scores: s_j[i] = q[r0+i] . k[d0+j]
    f32x4 s0=(f32x4)0.f, s1=(f32x4)0.f, s2=(f32x4)0.f, s3=(f32x4)0.f;
    #pragma unroll 4
    for (int d=0; d<64; d++){
      f32x4 qv = *(const f32x4*)&qsT[d*64 + r0];
      float ka = ksT[d*64 + d0+0];
      float kbb = ksT[d*64 + d0+1];
      float kc = ksT[d*64 + d0+2];
      float kd = ksT[d*64 + d0+3];
      s0 += qv * ka; s1 += qv * kbb; s2 += qv * kc; s3 += qv * kd;
    }
    if (kt == qt){
      #pragma unroll
      for (int i=0;i<4;i++){
        int qg = r0 + i;
        if (d0+0 > qg) s0[i] = -1e30f;
        if (d0+1 > qg) s1[i] = -1e30f;
        if (d0+2 > qg) s2[i] = -1e30f;
        if (d0+3 > qg) s3[i] = -1e30f;
      }
    }
    *(f32x4*)&psT[(d0+0)*64 + r0] = s0;
    *(f32x4*)&psT[(d0+1)*64 + r0] = s1;
    *(f32x4*)&psT[(d0+2)*64 + r0] = s2;
    *(f32x4*)&psT[(d0+3)*64 + r0] = s3;
    __syncthreads();

    // per-row tile max
    f32x4 rm = (f32x4)(-1e30f);
    for (int k=0;k<64;k++){
      f32x4 pv = *(const f32x4*)&psT[k*64 + r0];
      #pragma unroll
      for (int i=0;i<4;i++) rm[i] = fmaxf(rm[i], pv[i]);
    }
    f32x4 mnew, alpha;
    #pragma unroll
    for (int i=0;i<4;i++){
      mnew[i] = fmaxf(m4[i], rm[i]);
      alpha[i] = __expf(m4[i] - mnew[i]);
    }
    m4 = mnew;
    #pragma unroll
    for (int i=0;i<4;i++){ l4[i] *= alpha[i]; oacc[i] *= alpha[i]; }
    __syncthreads();  // all raw-score reads complete before overwrite

    // p = exp(s - mnew), write back
    #pragma unroll
    for (int i=0;i<4;i++){
      s0[i] = __expf(s0[i]-mnew[i]);
      s1[i] = __expf(s1[i]-mnew[i]);
      s2[i] = __expf(s2[i]-mnew[i]);
      s3[i] = __expf(s3[i]-mnew[i]);
    }
    *(f32x4*)&psT[(d0+0)*64 + r0] = s0;
    *(f32x4*)&psT[(d0+1)*64 + r0] = s1;
    *(f32x4*)&psT[(d0+2)*64 + r0] = s2;
    *(f32x4*)&psT[(d0+3)*64 + r0] = s3;
    __syncthreads();

    // PV: oacc[i][j] += p[k][i] * v[k][j], l += p
    for (int k=0;k<64;k++){
      f32x4 pv = *(const f32x4*)&psT[k*64 + r0];
      u32x2 vr = *(const u32x2*)&vsm[k*72 + d0];
      f32x4 vv;
      vv[0]=bf2f_u(vr[0]&0xffffu); vv[1]=bf2f_u(vr[0]>>16);
      vv[2]=bf2f_u(vr[1]&0xffffu); vv[3]=bf2f_u(vr[1]>>16);
      l4 += pv;
      #pragma unroll
      for (int i=0;i<4;i++) oacc[i] += vv * pv[i];
    }
  }

  #pragma unroll
  for (int i=0;i<4;i++){
    float inv = 1.f / l4[i];
    size_t base = (size_t)(b*1024 + qt*64 + r0 + i)*768 + h*64 + d0;
    unsigned int lo = (unsigned int)f2bf(oacc[i][0]*inv) | ((unsigned int)f2bf(oacc[i][1]*inv)<<16);
    unsigned int hi = (unsigned int)f2bf(oacc[i][2]*inv) | ((unsigned int)f2bf(oacc[i][3]*inv)<<16);
    u32x2 pv = {lo, hi};
    *(u32x2*)(O + base) = pv;
  }
}

// ---------------- launch ----------------
extern "C" void kernel_launch(void* const* d_in, const int* in_sizes, int n_in,
                              void* d_out, int out_size, void* d_ws, size_t ws_size,
                              hipStream_t stream) {
  const int*   ids    = (const int*)  d_in[0];
  const float* wte    = (const float*)d_in[1];
  const float* wpe    = (const float*)d_in[2];
  const float* ln1_g  = (const float*)d_in[3];
  const float* ln1_b  = (const float*)d_in[4];
  const float* w_attn = (const float*)d_in[5];
  const float* b_attn = (const float*)d_in[6];
  const float* w_proj = (const float*)d_in[7];
  const float* b_proj = (const float*)d_in[8];
  const float* ln2_g  = (const float*)d_in[9];
  const float* ln2_b  = (const float*)d_in[10];
  const float* w_fc   = (const float*)d_in[11];
  const float* b_fc   = (const float*)d_in[12];
  const float* w_mprj = (const float*)d_in[13];
  const float* b_mprj = (const float*)d_in[14];
  const float* lnf_g  = (const float*)d_in[15];
  const float* lnf_b  = (const float*)d_in[16];

  char* ws = (char*)d_ws;
  size_t off = 0;
  float*          x    = (float*)(ws + off);          off += (size_t)4096*768*4;
  unsigned short* h    = (unsigned short*)(ws + off); off += (size_t)4096*768*2;
  unsigned short* qkvb = (unsigned short*)(ws + off); off += (size_t)4096*2304*2;
  unsigned short* ob   = (unsigned short*)(ws + off); off += (size_t)4096*768*2;
  unsigned short* mid  = (unsigned short*)(ws + off); off += (size_t)4096*3072*2;
  size_t off_base = off;
  // optional bf16 weight mirrors
  unsigned short* wteb = (unsigned short*)(ws + off); off += (size_t)50257*768*2;
  unsigned short* wab  = (unsigned short*)(ws + off); off += (size_t)12*768*2304*2;
  unsigned short* wpb  = (unsigned short*)(ws + off); off += (size_t)12*768*768*2;
  unsigned short* wfb  = (unsigned short*)(ws + off); off += (size_t)12*768*3072*2;
  unsigned short* wmb  = (unsigned short*)(ws + off); off += (size_t)12*3072*768*2;
  size_t off_full = off;

  if (ws_size < off_base) return;  // workspace too small -> fail loudly via poisoned output
  const bool CW = (ws_size >= off_full);

  embed_k<<<4096, 256, 0, stream>>>(ids, wte, wpe, x);

  if (CW){
    cvt_k<<<2048, 256, 0, stream>>>(wte,    wteb, (size_t)50257*768/8);
    cvt_k<<<2048, 256, 0, stream>>>(w_attn, wab,  (size_t)12*768*2304/8);
    cvt_k<<<2048, 256, 0, stream>>>(w_proj, wpb,  (size_t)12*768*768/8);
    cvt_k<<<2048, 256, 0, stream>>>(w_fc,   wfb,  (size_t)12*768*3072/8);
    cvt_k<<<2048, 256, 0, stream>>>(w_mprj, wmb,  (size_t)12*3072*768/8);
  }

  for (int l = 0; l < 12; l++){
    ln_k<<<4096, 256, 0, stream>>>(x, ln1_g + l*768, ln1_b + l*768, h);
    if (CW)
      gemm_k<4,0,false,false,true,false,true><<<dim3(32,18), 256, 0, stream>>>(
          h, wab + (size_t)l*768*2304, b_attn + l*2304, nullptr, qkvb, 4096, 2304, 768);
    else
      gemm_k<4,0,false,false,true,false,false><<<dim3(32,18), 256, 0, stream>>>(
          h, w_attn + (size_t)l*768*2304, b_attn + l*2304, nullptr, qkvb, 4096, 2304, 768);
    attn_k<<<dim3(48,16), 256, 0, stream>>>(qkvb, ob);
    if (CW)
      gemm_k<2,0,true,false,false,false,true><<<dim3(64,6), 256, 0, stream>>>(
          ob, wpb + (size_t)l*768*768, b_proj + l*768, x, x, 4096, 768, 768);
    else
      gemm_k<2,0,true,false,false,false,false><<<dim3(64,6), 256, 0, stream>>>(
          ob, w_proj + (size_t)l*768*768, b_proj + l*768, x, x, 4096, 768, 768);
    ln_k<<<4096, 256, 0, stream>>>(x, ln2_g + l*768, ln2_b + l*768, h);
    if (CW)
      gemm_k<4,0,false,true,true,false,true><<<dim3(32,24), 256, 0, stream>>>(
          h, wfb + (size_t)l*768*3072, b_fc + l*3072, nullptr, mid, 4096, 3072, 768);
    else
      gemm_k<4,0,false,true,true,false,false><<<dim3(32,24), 256, 0, stream>>>(
          h, w_fc + (size_t)l*768*3072, b_fc + l*3072, nullptr, mid, 4096, 3072, 768);
    if (CW)
      gemm_k<2,0,true,false,false,false,true><<<dim3(64,6), 256, 0, stream>>>(
          mid, wmb + (size_t)l*3072*768, b_mprj + l*768, x, x, 4096, 768, 3072);
    else
      gemm_k<2,0,true,false,false,false,false><<<dim3(64,6), 256, 0, stream>>>(
          mid, w_mprj + (size_t)l*3072*768, b_mprj + l*768, x, x, 4096, 768, 3072);
  }

  ln_k<<<4096, 256, 0, stream>>>(x, lnf_g, lnf_b, h);
  if (CW)
    gemm_k<4,1,false,false,false,true,true><<<dim3(32,393), 256, 0, stream>>>(
        h, wteb, nullptr, nullptr, (float*)d_out, 4096, 50257, 768);
  else
    gemm_k<4,1,false,false,false,true,false><<<dim3(32,393), 256, 0, stream>>>(
        h, wte, nullptr, nullptr, (float*)d_out, 4096, 50257, 768);
}

// Round 2
// 4569.509 us; speedup vs baseline: 1.3577x; 1.3577x over previous
//
#include <hip/hip_runtime.h>

// GPT-2 small forward on gfx950. bf16 MFMA GEMMs, fp32 residual stream.
// Layout notes (HW-verified per guide):
//   mfma_f32_16x16x32_bf16: A/B frag: elem j of lane L = M[L&15][(L>>4)*8+j]
//   C/D: reg r of lane L = C[(L>>4)*4 + r][L&15]
// R1: weights pre-converted to bf16 once (cvt_k) -> gemm_k<BF16B=true>.
// R2: attn_k rewritten to MFMA (QK^T and PV on matrix pipe instead of fp32 VALU).

typedef __attribute__((ext_vector_type(4))) float f32x4;
typedef __attribute__((ext_vector_type(8))) short short8;
typedef __attribute__((ext_vector_type(4))) unsigned int u32x4;
typedef __attribute__((ext_vector_type(2))) unsigned int u32x2;

__device__ __forceinline__ float bf2f_u(unsigned int lo16){
  union { unsigned int i; float f; } v; v.i = lo16 << 16; return v.f;
}
__device__ __forceinline__ unsigned short f2bf(float x){
  union { float f; unsigned int i; } v; v.f = x;
  unsigned int i = v.i;
  return (unsigned short)((i + 0x7fffu + ((i >> 16) & 1u)) >> 16);
}
__device__ __forceinline__ int swz(int row){ return (row >> 1) & 3; }

// ---------------- f32 -> bf16 bulk convert ----------------
__global__ __launch_bounds__(256) void cvt_k(const float* __restrict__ src,
    unsigned short* __restrict__ dst, size_t n8){
  size_t i = (size_t)blockIdx.x * 256 + threadIdx.x;
  size_t stride = (size_t)gridDim.x * 256;
  for (; i < n8; i += stride){
    const f32x4* s = (const f32x4*)(src + i*8);
    f32x4 a = s[0], b = s[1];
    u32x4 o;
    o[0] = (unsigned int)f2bf(a[0]) | ((unsigned int)f2bf(a[1]) << 16);
    o[1] = (unsigned int)f2bf(a[2]) | ((unsigned int)f2bf(a[3]) << 16);
    o[2] = (unsigned int)f2bf(b[0]) | ((unsigned int)f2bf(b[1]) << 16);
    o[3] = (unsigned int)f2bf(b[2]) | ((unsigned int)f2bf(b[3]) << 16);
    *(u32x4*)(dst + i*8) = o;
  }
}

// ---------------- embedding ----------------
__global__ __launch_bounds__(256) void embed_k(const int* __restrict__ ids,
    const float* __restrict__ wte, const float* __restrict__ wpe, float* __restrict__ x){
  int tok = blockIdx.x, t = threadIdx.x;
  int id = ids[tok]; int pos = tok & 1023;
  const float* we = wte + (size_t)id * 768;
  const float* pe = wpe + (size_t)pos * 768;
  float* xo = x + (size_t)tok * 768;
  #pragma unroll
  for (int j = 0; j < 3; j++){ int c = t + j*256; xo[c] = we[c] + pe[c]; }
}

// ---------------- layernorm -> bf16 ----------------
__global__ __launch_bounds__(256) void ln_k(const float* __restrict__ X,
    const float* __restrict__ g, const float* __restrict__ bta, unsigned short* __restrict__ H){
  int row = blockIdx.x, t = threadIdx.x;
  const float* xr = X + (size_t)row * 768;
  float v0 = xr[t], v1 = xr[t+256], v2 = xr[t+512];
  float s = v0+v1+v2;
  float ss = v0*v0+v1*v1+v2*v2;
  #pragma unroll
  for (int o = 32; o > 0; o >>= 1){ s += __shfl_xor(s, o, 64); ss += __shfl_xor(ss, o, 64); }
  __shared__ float rs_[4], rq_[4];
  int w = t >> 6;
  if ((t & 63) == 0){ rs_[w] = s; rq_[w] = ss; }
  __syncthreads();
  s  = rs_[0]+rs_[1]+rs_[2]+rs_[3];
  ss = rq_[0]+rq_[1]+rq_[2]+rq_[3];
  float mu = s * (1.f/768.f);
  float var = ss * (1.f/768.f) - mu*mu;
  float r = rsqrtf(var + 1e-5f);
  unsigned short* ho = H + (size_t)row*768;
  float vv[3] = {v0, v1, v2};
  #pragma unroll
  for (int j=0;j<3;j++){ int c = t + j*256; ho[c] = f2bf((vv[j] - mu)*r*g[c] + bta[c]); }
}

// ---------------- GEMM: C[M,N] = A(bf16)[M,K] @ B (+bias)(+gelu)(+resid) ----------------
// BL=0: B is [K,N] row-major.  BL=1: B is [N,K] row-major (lm_head, B=wte).
// BF16B=1: B is pre-converted bf16; staging is bit-repack only (no f2bf).
template<int TM, int BL, bool RESID, bool GELU_ACT, bool OUTBF16, bool NGUARD, bool BF16B>
__global__ __launch_bounds__(256, 2) void gemm_k(
    const unsigned short* __restrict__ A, const void* __restrict__ Bw,
    const float* __restrict__ bias, const float* __restrict__ resid,
    void* __restrict__ Cp, int M, int N, int K)
{
  constexpr int BM = TM * 32;
  __shared__ __align__(16) unsigned short As[128*32];
  __shared__ __align__(16) unsigned short Bs[128*32];
  const int tid = threadIdx.x;
  const int m0 = blockIdx.x * BM, n0 = blockIdx.y * 128;
  const int lane = tid & 63, w = tid >> 6;
  const int quad = lane >> 4, lr = lane & 15;
  const int wm = (w >> 1) * (TM*16), wn = (w & 1) * 64;

  f32x4 acc[TM][4];
  #pragma unroll
  for (int i=0;i<TM;i++)
    #pragma unroll
    for (int j=0;j<4;j++) acc[i][j] = (f32x4)0.f;

  // staging registers
  u32x4 aReg[TM/2 > 0 ? TM/2 : 1];
  float bReg[16];
  u32x2 bRegH[4];
  u32x4 bRegQ[2];
  const int kb = (tid >> 5) * 4;        // BL==0
  const int nn = (tid & 31) * 4;        // BL==0
  const int nr = tid >> 1;              // BL==1
  const int kk = (tid & 1) * 16;        // BL==1

  auto loadA = [&](int k0){
    #pragma unroll
    for (int j = 0; j < TM/2; j++){
      int idx = tid * (TM/2) + j;
      int row = idx >> 2, b = idx & 3;
      aReg[j] = *(const u32x4*)(A + (size_t)(m0+row)*K + k0 + b*8);
    }
  };
  auto loadB = [&](int k0){
    if (BF16B){
      const unsigned short* Bh = (const unsigned short*)Bw;
      if (BL == 0){
        #pragma unroll
        for (int i=0;i<4;i++)
          bRegH[i] = *(const u32x2*)(Bh + (size_t)(k0+kb+i)*N + n0 + nn);
      } else {
        int gn = n0 + nr;
        if (!NGUARD || gn < N){
          bRegQ[0] = *(const u32x4*)(Bh + (size_t)gn*K + k0 + kk);
          bRegQ[1] = *(const u32x4*)(Bh + (size_t)gn*K + k0 + kk + 8);
        } else {
          bRegQ[0] = (u32x4)0u; bRegQ[1] = (u32x4)0u;
        }
      }
    } else {
      const float* Bf = (const float*)Bw;
      if (BL == 0){
        #pragma unroll
        for (int i=0;i<4;i++){
          f32x4 v = *(const f32x4*)(Bf + (size_t)(k0+kb+i)*N + n0 + nn);
          #pragma unroll
          for (int j=0;j<4;j++) bReg[i*4+j] = v[j];
        }
      } else {
        int gn = n0 + nr;
        if (!NGUARD || gn < N){
          #pragma unroll
          for (int q2=0;q2<4;q2++){
            f32x4 v = *(const f32x4*)(Bf + (size_t)gn*K + k0 + kk + q2*4);
            #pragma unroll
            for (int j=0;j<4;j++) bReg[q2*4+j] = v[j];
          }
        } else {
          #pragma unroll
          for (int q2=0;q2<16;q2++) bReg[q2] = 0.f;
        }
      }
    }
  };
  auto storeA = [&](){
    #pragma unroll
    for (int j=0;j<TM/2;j++){
      int idx = tid*(TM/2)+j;
      int row = idx>>2, b = idx&3;
      int off = row*64 + ((b ^ swz(row))<<4);
      *(u32x4*)((char*)As + off) = aReg[j];
    }
  };
  auto storeB = [&](){
    if (BF16B){
      if (BL == 0){
        int blk = kb >> 3;
        #pragma unroll
        for (int j=0;j<4;j++){
          int row = nn + j;
          unsigned int e0 = (bRegH[0][j>>1] >> ((j&1)*16)) & 0xffffu;
          unsigned int e1 = (bRegH[1][j>>1] >> ((j&1)*16)) & 0xffffu;
          unsigned int e2 = (bRegH[2][j>>1] >> ((j&1)*16)) & 0xffffu;
          unsigned int e3 = (bRegH[3][j>>1] >> ((j&1)*16)) & 0xffffu;
          int off = row*64 + ((blk ^ swz(row)) << 4) + (kb & 7)*2;
          u32x2 pv = {e0 | (e1 << 16), e2 | (e3 << 16)};
          *(u32x2*)((char*)Bs + off) = pv;
        }
      } else {
        #pragma unroll
        for (int half=0; half<2; half++){
          int blk = (kk >> 3) + half;
          int off = nr*64 + ((blk ^ swz(nr)) << 4);
          *(u32x4*)((char*)Bs + off) = bRegQ[half];
        }
      }
    } else {
      if (BL == 0){
        int blk = kb >> 3;
        #pragma unroll
        for (int j=0;j<4;j++){
          int row = nn + j;
          unsigned int lo = (unsigned int)f2bf(bReg[0*4+j]) | ((unsigned int)f2bf(bReg[1*4+j]) << 16);
          unsigned int hi = (unsigned int)f2bf(bReg[2*4+j]) | ((unsigned int)f2bf(bReg[3*4+j]) << 16);
          int off = row*64 + ((blk ^ swz(row)) << 4) + (kb & 7)*2;
          u32x2 pv = {lo, hi};
          *(u32x2*)((char*)Bs + off) = pv;
        }
      } else {
        int row = nr;
        #pragma unroll
        for (int half=0; half<2; half++){
          unsigned int w0 = (unsigned int)f2bf(bReg[half*8+0]) | ((unsigned int)f2bf(bReg[half*8+1])<<16);
          unsigned int w1 = (unsigned int)f2bf(bReg[half*8+2]) | ((unsigned int)f2bf(bReg[half*8+3])<<16);
          unsigned int w2 = (unsigned int)f2bf(bReg[half*8+4]) | ((unsigned int)f2bf(bReg[half*8+5])<<16);
          unsigned int w3 = (unsigned int)f2bf(bReg[half*8+6]) | ((unsigned int)f2bf(bReg[half*8+7])<<16);
          int blk = (kk >> 3) + half;
          int off = row*64 + ((blk ^ swz(row)) << 4);
          u32x4 pv = {w0,w1,w2,w3};
          *(u32x4*)((char*)Bs + off) = pv;
        }
      }
    }
  };

  loadA(0); loadB(0);
  const int nK = K / 32;
  for (int kt = 0; kt < nK; kt++){
    __syncthreads();
    storeA(); storeB();
    __syncthreads();
    if (kt + 1 < nK){ loadA((kt+1)*32); loadB((kt+1)*32); }
    short8 af[TM], bfr[4];
    #pragma unroll
    for (int i=0;i<TM;i++){
      int row = wm + i*16 + lr;
      af[i] = *(const short8*)((const char*)As + row*64 + ((quad ^ swz(row))<<4));
    }
    #pragma unroll
    for (int j=0;j<4;j++){
      int col = wn + j*16 + lr;
      bfr[j] = *(const short8*)((const char*)Bs + col*64 + ((quad ^ swz(col))<<4));
    }
    #pragma unroll
    for (int i=0;i<TM;i++)
      #pragma unroll
      for (int j=0;j<4;j++)
        acc[i][j] = __builtin_amdgcn_mfma_f32_16x16x32_bf16(af[i], bfr[j], acc[i][j], 0, 0, 0);
  }

  // epilogue
  #pragma unroll
  for (int i=0;i<TM;i++){
    #pragma unroll
    for (int j=0;j<4;j++){
      int col = n0 + wn + j*16 + lr;
      bool ok = !NGUARD || (col < N);
      float bv = 0.f;
      if (bias != nullptr && ok) bv = bias[col];
      #pragma unroll
      for (int r2=0;r2<4;r2++){
        int row = m0 + wm + i*16 + quad*4 + r2;
        float v = acc[i][j][r2] + bv;
        if (GELU_ACT){
          float x3 = v*v*v;
          v = 0.5f*v*(1.f + tanhf(0.7978845608028654f*(v + 0.044715f*x3)));
        }
        if (RESID && ok) v += resid[(size_t)row*N + col];
        if (ok){
          if (OUTBF16) ((unsigned short*)Cp)[(size_t)row*N + col] = f2bf(v);
          else         ((float*)Cp)[(size_t)row*N + col] = v;
        }
      }
    }
  }
}

// ---------------- causal attention (flash-style, MFMA bf16) ----------------
// grid (48 = b*h, 16 = q-tiles of 64). 256 threads = 4 waves; wave w owns
// q rows [qt*64 + w*16, +16). KVBLK=64 per iteration.
// Fragment layouts (HW-verified): A/B elem j of lane L = M[L&15][(L>>4)*8+j];
// C/D reg r of lane L = C[(L>>4)*4+r][L&15].
// LDS rows are 64 bf16 = 128B -> XOR-swizzle byte offset by ((row&7)<<4)
// (G4: otherwise ds_read_b128 at 128B stride is a full bank conflict).
__global__ __launch_bounds__(256, 2) void attn_k(const unsigned short* __restrict__ qkv,
                                                 unsigned short* __restrict__ O){
  __shared__ __align__(16) unsigned short Ks[64*64];      // [key][d]   swizzled
  __shared__ __align__(16) unsigned short Vt[64*64];      // [d][key]   swizzled
  __shared__ __align__(16) unsigned short Ps[4*16*64];    // per-wave [q][k] swizzled
  const int bh = blockIdx.x, qt = blockIdx.y;
  const int b = bh / 12, h = bh % 12;
  const int tid = threadIdx.x;
  const int w = tid >> 6, lane = tid & 63;
  const int lr = lane & 15, quad = lane >> 4;

  // Q fragments in registers (row = lr within wave's 16 rows)
  short8 aq0, aq1;
  {
    const unsigned short* qp = qkv + (size_t)(b*1024 + qt*64 + w*16 + lr)*2304 + h*64 + quad*8;
    aq0 = *(const short8*)qp;
    aq1 = *(const short8*)(qp + 32);
  }

  f32x4 oacc[4];               // d-subtile jj: O[quad*4+r][jj*16+lr]
  #pragma unroll
  for (int j=0;j<4;j++) oacc[j] = (f32x4)0.f;
  f32x4 m4 = (f32x4)(-1e30f);  // per q-row (quad*4+r) running max
  f32x4 l4 = (f32x4)0.f;

  unsigned short* ps = Ps + w*1024;   // wave-private 16x64 bf16

  const int stage_key = tid >> 2, stage_dc = (tid & 3) * 16;
  const unsigned short* kvbase = qkv + (size_t)(b*1024 + stage_key)*2304 + 768 + h*64 + stage_dc;

  for (int kt = 0; kt <= qt; kt++){
    __syncthreads();   // previous iteration's frag reads done
    { // stage K [key][d] and V transposed [d][key], both bf16 + swizzled
      const unsigned short* kp = kvbase + (size_t)kt*64*2304;
      u32x4 k0 = *(const u32x4*)kp;
      u32x4 k1 = *(const u32x4*)(kp + 8);
      int ko = stage_key*128 + stage_dc*2;
      int kx = (stage_key & 7) << 4;
      *(u32x4*)((char*)Ks + (ko ^ kx)) = k0;
      *(u32x4*)((char*)Ks + ((ko + 16) ^ kx)) = k1;
      u32x4 v0 = *(const u32x4*)(kp + 768);
      u32x4 v1 = *(const u32x4*)(kp + 768 + 8);
      #pragma unroll
      for (int i=0;i<8;i++){
        int d = stage_dc + i;
        int off = (d*128 + stage_key*2) ^ ((d & 7) << 4);
        *(unsigned short*)((char*)Vt + off) = (unsigned short)((v0[i>>1] >> ((i&1)*16)) & 0xffffu);
      }
      #pragma unroll
      for (int i=0;i<8;i++){
        int d = stage_dc + 8 + i;
        int off = (d*128 + stage_key*2) ^ ((d & 7) << 4);
        *(unsigned short*)((char*)Vt + off) = (unsigned short)((v1[i>>1] >> ((i&1)*16)) & 0xffffu);
      }
    }
    __syncthreads();

    // S = Q K^T (per wave: 16 q x 64 keys), subtile ss = 16 keys
    f32x4 s[4];
    #pragma unroll
    for (int ss=0; ss<4; ss++){
      int krow = ss*16 + lr;
      int kx = (krow & 7) << 4;
      int base = krow*128 + quad*16;
      short8 bk0 = *(const short8*)((const char*)Ks + (base ^ kx));
      short8 bk1 = *(const short8*)((const char*)Ks + ((base + 64) ^ kx));
      f32x4 acc = (f32x4)0.f;
      acc = __builtin_amdgcn_mfma_f32_16x16x32_bf16(aq0, bk0, acc, 0, 0, 0);
      acc = __builtin_amdgcn_mfma_f32_16x16x32_bf16(aq1, bk1, acc, 0, 0, 0);
      s[ss] = acc * 0.125f;    // 1/sqrt(64)
    }

    if (kt == qt){ // causal mask within diagonal tile
      #pragma unroll
      for (int ss=0;ss<4;ss++){
        int k = ss*16 + lr;
        #pragma unroll
        for (int r=0;r<4;r++){
          int q = w*16 + quad*4 + r;
          if (k > q) s[ss][r] = -1e30f;
        }
      }
    }

    // per-row max over 64 keys: local over subtiles, then 16-lane butterfly
    f32x4 mnew, alpha;
    #pragma unroll
    for (int r=0;r<4;r++){
      float v = fmaxf(fmaxf(s[0][r], s[1][r]), fmaxf(s[2][r], s[3][r]));
      #pragma unroll
      for (int o=1;o<16;o<<=1) v = fmaxf(v, __shfl_xor(v, o, 64));
      mnew[r] = fmaxf(m4[r], v);
      alpha[r] = __expf(m4[r] - mnew[r]);
    }
    m4 = mnew;

    // P = exp(S - m), row sums, rescale O and l
    #pragma unroll
    for (int ss=0;ss<4;ss++)
      #pragma unroll
      for (int r=0;r<4;r++)
        s[ss][r] = __expf(s[ss][r] - mnew[r]);
    #pragma unroll
    for (int r=0;r<4;r++){
      float v = s[0][r]+s[1][r]+s[2][r]+s[3][r];
      #pragma unroll
      for (int o=1;o<16;o<<=1) v += __shfl_xor(v, o, 64);
      l4[r] = l4[r]*alpha[r] + v;
    }
    #pragma unroll
    for (int jj=0;jj<4;jj++)
      #pragma unroll
      for (int r=0;r<4;r++) oacc[jj][r] *= alpha[r];

    // P (bf16) -> wave-private LDS to reshape into A-fragments
    #pragma unroll
    for (int ss=0;ss<4;ss++){
      #pragma unroll
      for (int r=0;r<4;r++){
        int q = quad*4 + r, k = ss*16 + lr;
        int off = (q*128 + k*2) ^ ((q & 7) << 4);
        *(unsigned short*)((char*)ps + off) = f2bf(s[ss][r]);
      }
    }
    // (wave-private: no barrier; compiler orders ds_write->ds_read)
    short8 pa0, pa1;
    {
      int qx = (lr & 7) << 4;
      int base = lr*128 + quad*16;
      pa0 = *(const short8*)((const char*)ps + (base ^ qx));
      pa1 = *(const short8*)((const char*)ps + ((base + 64) ^ qx));
    }
    // O += P V : B-frag from Vt (V columns are Vt rows)
    #pragma unroll
    for (int jj=0;jj<4;jj++){
      int drow = jj*16 + lr;
      int dx = (drow & 7) << 4;
      int base = drow*128 + quad*16;
      short8 bv0 = *(const short8*)((const char*)Vt + (base ^ dx));
      short8 bv1 = *(const short8*)((const char*)Vt + ((base + 64) ^ dx));
      oacc[jj] = __builtin_amdgcn_mfma_f32_16x16x32_bf16(pa0, bv0, oacc[jj], 0, 0, 0);
      oacc[jj] = __builtin_amdgcn_mfma_f32_16x16x32_bf16(pa1, bv1, oacc[jj], 0, 0, 0);
    }
  }

  // epilogue: normalize and store
  #pragma unroll
  for (int r=0;r<4;r++){
    float inv = 1.f / l4[r];
    size_t base = (size_t)(b*1024 + qt*64 + w*16 + quad*4 + r)*768 + h*64 + lr;
    #pragma unroll
    for (int jj=0;jj<4;jj++)
      O[base + jj*16] = f2bf(oacc[jj][r] * inv);
  }
}

// ---------------- launch ----------------
extern "C" void kernel_launch(void* const* d_in, const int* in_sizes, int n_in,
                              void* d_out, int out_size, void* d_ws, size_t ws_size,
                              hipStream_t stream) {
  const int*   ids    = (const int*)  d_in[0];
  const float* wte    = (const float*)d_in[1];
  const float* wpe    = (const float*)d_in[2];
  const float* ln1_g  = (const float*)d_in[3];
  const float* ln1_b  = (const float*)d_in[4];
  const float* w_attn = (const float*)d_in[5];
  const float* b_attn = (const float*)d_in[6];
  const float* w_proj = (const float*)d_in[7];
  const float* b_proj = (const float*)d_in[8];
  const float* ln2_g  = (const float*)d_in[9];
  const float* ln2_b  = (const float*)d_in[10];
  const float* w_fc   = (const float*)d_in[11];
  const float* b_fc   = (const float*)d_in[12];
  const float* w_mprj = (const float*)d_in[13];
  const float* b_mprj = (const float*)d_in[14];
  const float* lnf_g  = (const float*)d_in[15];
  const float* lnf_b  = (const float*)d_in[16];

  char* ws = (char*)d_ws;
  size_t off = 0;
  float*          x    = (float*)(ws + off);          off += (size_t)4096*768*4;
  unsigned short* h    = (unsigned short*)(ws + off); off += (size_t)4096*768*2;
  unsigned short* qkvb = (unsigned short*)(ws + off); off += (size_t)4096*2304*2;
  unsigned short* ob   = (unsigned short*)(ws + off); off += (size_t)4096*768*2;
  unsigned short* mid  = (unsigned short*)(ws + off); off += (size_t)4096*3072*2;
  size_t off_base = off;
  // optional bf16 weight mirrors
  unsigned short* wteb = (unsigned short*)(ws + off); off += (size_t)50257*768*2;
  unsigned short* wab  = (unsigned short*)(ws + off); off += (size_t)12*768*2304*2;
  unsigned short* wpb  = (unsigned short*)(ws + off); off += (size_t)12*768*768*2;
  unsigned short* wfb  = (unsigned short*)(ws + off); off += (size_t)12*768*3072*2;
  unsigned short* wmb  = (unsigned short*)(ws + off); off += (size_t)12*3072*768*2;
  size_t off_full = off;

  if (ws_size < off_base) return;  // workspace too small -> fail loudly via poisoned output
  const bool CW = (ws_size >= off_full);

  embed_k<<<4096, 256, 0, stream>>>(ids, wte, wpe, x);

  if (CW){
    cvt_k<<<2048, 256, 0, stream>>>(wte,    wteb, (size_t)50257*768/8);
    cvt_k<<<2048, 256, 0, stream>>>(w_attn, wab,  (size_t)12*768*2304/8);
    cvt_k<<<2048, 256, 0, stream>>>(w_proj, wpb,  (size_t)12*768*768/8);
    cvt_k<<<2048, 256, 0, stream>>>(w_fc,   wfb,  (size_t)12*768*3072/8);
    cvt_k<<<2048, 256, 0, stream>>>(w_mprj, wmb,  (size_t)12*3072*768/8);
  }

  for (int l = 0; l < 12; l++){
    ln_k<<<4096, 256, 0, stream>>>(x, ln1_g + l*768, ln1_b + l*768, h);
    if (CW)
      gemm_k<4,0,false,false,true,false,true><<<dim3(32,18), 256, 0, stream>>>(
          h, wab + (size_t)l*768*2304, b_attn + l*2304, nullptr, qkvb, 4096, 2304, 768);
    else
      gemm_k<4,0,false,false,true,false,false><<<dim3(32,18), 256, 0, stream>>>(
          h, w_attn + (size_t)l*768*2304, b_attn + l*2304, nullptr, qkvb, 4096, 2304, 768);
    attn_k<<<dim3(48,16), 256, 0, stream>>>(qkvb, ob);
    if (CW)
      gemm_k<2,0,true,false,false,false,true><<<dim3(64,6), 256, 0, stream>>>(
          ob, wpb + (size_t)l*768*768, b_proj + l*768, x, x, 4096, 768, 768);
    else
      gemm_k<2,0,true,false,false,false,false><<<dim3(64,6), 256, 0, stream>>>(
          ob, w_proj + (size_t)l*768*768, b_proj + l*768, x, x, 4096, 768, 768);
    ln_k<<<4096, 256, 0, stream>>>(x, ln2_g + l*768, ln2_b + l*768, h);
    if (CW)
      gemm_k<4,0,false,true,true,false,true><<<dim3(32,24), 256, 0, stream>>>(
          h, wfb + (size_t)l*768*3072, b_fc + l*3072, nullptr, mid, 4096, 3072, 768);
    else
      gemm_k<4,0,false,true,true,false,false><<<dim3(32,24), 256, 0, stream>>>(
          h, w_fc + (size_t)l*768*3072, b_fc + l*3072, nullptr, mid, 4096, 3072, 768);
    if (CW)
      gemm_k<2,0,true,false,false,false,true><<<dim3(64,6), 256, 0, stream>>>(
          mid, wmb + (size_t)l*3072*768, b_mprj + l*768, x, x, 4096, 768, 3072);
    else
      gemm_k<2,0,true,false,false,false,false><<<dim3(64,6), 256, 0, stream>>>(
          mid, w_mprj + (size_t)l*3072*768, b_mprj + l*768, x, x, 4096, 768, 3072);
  }

  ln_k<<<4096, 256, 0, stream>>>(x, lnf_g, lnf_b, h);
  if (CW)
    gemm_k<4,1,false,false,false,true,true><<<dim3(32,393), 256, 0, stream>>>(
        h, wteb, nullptr, nullptr, (float*)d_out, 4096, 50257, 768);
  else
    gemm_k<4,1,false,false,false,true,false><<<dim3(32,393), 256, 0, stream>>>(
        h, wte, nullptr, nullptr, (float*)d_out, 4096, 50257, 768);
}